// Round 2
// baseline (155.294 us; speedup 1.0000x reference)
//
#include <hip/hip_runtime.h>

#define GB 64
#define GN 128
#define F_OBS 64
#define F_TOT 80
#define ISPLIT 32
#define IPB (GN / ISPLIT)   // 4 i-rows per block

// Single fused kernel. Block = 128 threads (2 waves), thread = column j.
// Block (b, is..is+3): A[b,i,j] for its i-tile, plus a deterministic partial
// of the off-diagonal log-likelihood. Last-arriving block per batch (via a
// device-scope arrival counter) sums the 32 partials in FIXED index order ->
// bitwise-deterministic probs without a second dependent dispatch.
__global__ __launch_bounds__(128) void glcn_fused(
    const float* __restrict__ h, const float* __restrict__ w,
    float* __restrict__ Aout, float* __restrict__ probs,
    float* __restrict__ part, int* __restrict__ cnt) {
  const int blk = blockIdx.x;
  const int b  = blk >> 5;                    // / ISPLIT
  const int is = (blk & (ISPLIT - 1)) * IPB;
  const int j  = threadIdx.x;                 // 0..127

  // Own row h[b, j, 0:64] -> 64 VGPRs (float4 loads; row stride 320B aligned).
  float hj[F_OBS];
  const float* rowj = h + ((size_t)(b * GN + j)) * F_TOT;
#pragma unroll
  for (int q = 0; q < F_OBS / 4; ++q) {
    float4 v = *reinterpret_cast<const float4*>(rowj + q * 4);
    hj[q * 4 + 0] = v.x; hj[q * 4 + 1] = v.y;
    hj[q * 4 + 2] = v.z; hj[q * 4 + 3] = v.w;
  }

  float logsum = 0.f;
#pragma unroll
  for (int ii = 0; ii < IPB; ++ii) {
    const int i = is + ii;
    // rowi[k], w[k] are block-uniform -> scalar loads; inner body is
    // v_sub + v_fma with |.| input modifier: 2 VALU per MAC, no LDS.
    const float* rowi = h + ((size_t)(b * GN + i)) * F_TOT;
    float a0 = 0.f, a1 = 0.f;   // 2 accumulators: break the fma dep chain
#pragma unroll
    for (int k = 0; k < F_OBS; k += 2) {
      a0 = fmaf(w[k],     fabsf(hj[k]     - rowi[k]),     a0);
      a1 = fmaf(w[k + 1], fabsf(hj[k + 1] - rowi[k + 1]), a1);
    }
    const float acc = a0 + a1;
    const float ysoft = 1.f / (1.f + __expf(-acc));
    float Aval = (ysoft > 0.5f) ? 1.f : 0.f;
    const float sel = (Aval != 0.f) ? ysoft : (1.f - ysoft);
    const float lt = __logf(sel + 1e-8f);
    if (i == j) Aval = 1.f;     // diagonal: forced 1, excluded from log-sum
    else        logsum += lt;
    Aout[((size_t)(b * GN + i)) * GN + j] = Aval;   // lanes=j: coalesced
  }

  // Deterministic block reduction (fixed shuffle-tree order).
#pragma unroll
  for (int off = 32; off > 0; off >>= 1)
    logsum += __shfl_down(logsum, off, 64);
  __shared__ float red[2];
  const int lane = threadIdx.x & 63;
  const int wid  = threadIdx.x >> 6;
  if (lane == 0) red[wid] = logsum;
  __syncthreads();
  if (threadIdx.x == 0) {
    __hip_atomic_store(&part[blk], red[0] + red[1],
                       __ATOMIC_RELAXED, __HIP_MEMORY_SCOPE_AGENT);
  }
  __threadfence();   // make partial visible device-wide before arrival mark

  int last = 0;
  if (threadIdx.x == 0) {
    int old = __hip_atomic_fetch_add(&cnt[b], 1, __ATOMIC_ACQ_REL,
                                     __HIP_MEMORY_SCOPE_AGENT);
    last = (old == ISPLIT - 1);
  }
  last = __shfl(last, 0, 64);   // broadcast within wave 0
  if (last && threadIdx.x < 32) {
    // All 32 partials are visible (each writer fenced before incrementing).
    float v = __hip_atomic_load(&part[b * ISPLIT + threadIdx.x],
                                __ATOMIC_RELAXED, __HIP_MEMORY_SCOPE_AGENT);
#pragma unroll
    for (int off = 16; off > 0; off >>= 1)
      v += __shfl_down(v, off, 64);
    if (threadIdx.x == 0) probs[b] = v;
  }
}

extern "C" void kernel_launch(void* const* d_in, const int* in_sizes, int n_in,
                              void* d_out, int out_size, void* d_ws, size_t ws_size,
                              hipStream_t stream) {
  const float* h = (const float*)d_in[0];   // [64,128,80] f32
  const float* w = (const float*)d_in[1];   // [64,1] f32
  float* Aout  = (float*)d_out;                       // [64,128,128]
  float* probs = Aout + (size_t)GB * GN * GN;         // [64]
  float* part  = (float*)d_ws;                        // GB*ISPLIT floats
  int*   cnt   = (int*)((char*)d_ws + GB * ISPLIT * sizeof(float));

  // Zero the 64 arrival counters each call (graph-capture-safe).
  hipMemsetAsync(cnt, 0, GB * sizeof(int), stream);
  glcn_fused<<<GB * ISPLIT, 128, 0, stream>>>(h, w, Aout, probs, part, cnt);
}

// Round 3
// 41.421 us; speedup vs baseline: 3.7491x; 3.7491x over previous
//
#include <hip/hip_runtime.h>

#define GB 64
#define GN 128
#define F_OBS 64
#define F_TOT 80
#define NTHREADS 1024
#define NWAVES (NTHREADS / 64)
#define IPT 16   // i-rows per thread: GN / (NTHREADS/GN)

// One block per batch (grid=64, 16 waves). Thread (it, j): j = column,
// it = i-group; handles i in [16*it, 16*it+16). Within a wave both it and i
// are uniform -> rowi/w become scalar loads; hj stays in VGPRs, so the inner
// MAC is v_sub(v,s) + v_fma(abs(v),s,v): 2 VALU/MAC, max 1 SGPR operand each.
// probs[b] is reduced entirely intra-block in fixed order (shfl tree + LDS,
// thread 0 sums the 16 wave partials in index order) -> deterministic, and
// NO cross-block fences/atomics (round-2's 7x regression was device-scope
// ordering cost on non-coherent per-XCD L2s).
__global__ __launch_bounds__(NTHREADS, 4) void glcn_one(
    const float* __restrict__ h, const float* __restrict__ w,
    float* __restrict__ Aout, float* __restrict__ probs) {
  const int b  = blockIdx.x;
  const int j  = threadIdx.x & (GN - 1);
  const int it = threadIdx.x >> 7;           // 0..7, wave-uniform

  // Own row h[b, j, 0:64] -> 64 VGPRs (float4 loads; row stride 320B aligned).
  float hj[F_OBS];
  const float* rowj = h + ((size_t)(b * GN + j)) * F_TOT;
#pragma unroll
  for (int q = 0; q < F_OBS / 4; ++q) {
    float4 v = *reinterpret_cast<const float4*>(rowj + q * 4);
    hj[q * 4 + 0] = v.x; hj[q * 4 + 1] = v.y;
    hj[q * 4 + 2] = v.z; hj[q * 4 + 3] = v.w;
  }

  float logsum = 0.f;
  float* Abase = Aout + (size_t)b * GN * GN;
#pragma unroll 4
  for (int ii = 0; ii < IPT; ++ii) {
    const int i = it * IPT + ii;
    const float* rowi = h + ((size_t)(b * GN + i)) * F_TOT;
    float a0 = 0.f, a1 = 0.f;   // 2 accumulators: break the fma dep chain
#pragma unroll
    for (int k = 0; k < F_OBS; k += 2) {
      a0 = fmaf(w[k],     fabsf(hj[k]     - rowi[k]),     a0);
      a1 = fmaf(w[k + 1], fabsf(hj[k + 1] - rowi[k + 1]), a1);
    }
    const float acc = a0 + a1;
    // gumbel_sigmoid, rollout: y_soft = sigmoid(logit), hard threshold 0.5
    const float ysoft = 1.f / (1.f + __expf(-acc));
    float Aval = (ysoft > 0.5f) ? 1.f : 0.f;
    const float sel = (Aval != 0.f) ? ysoft : (1.f - ysoft);
    const float lt = __logf(sel + 1e-8f);
    if (i == j) Aval = 1.f;     // diagonal: forced 1, excluded from log-sum
    else        logsum += lt;
    Abase[(size_t)i * GN + j] = Aval;   // lanes=j: coalesced 256B stores
  }

  // Deterministic intra-block reduction: wave shfl tree, then thread 0 sums
  // the 16 wave partials in fixed index order.
#pragma unroll
  for (int off = 32; off > 0; off >>= 1)
    logsum += __shfl_down(logsum, off, 64);
  __shared__ float red[NWAVES];
  const int lane = threadIdx.x & 63;
  const int wid  = threadIdx.x >> 6;
  if (lane == 0) red[wid] = logsum;
  __syncthreads();
  if (threadIdx.x == 0) {
    float s = 0.f;
#pragma unroll
    for (int q = 0; q < NWAVES; ++q) s += red[q];
    probs[b] = s;
  }
}

extern "C" void kernel_launch(void* const* d_in, const int* in_sizes, int n_in,
                              void* d_out, int out_size, void* d_ws, size_t ws_size,
                              hipStream_t stream) {
  const float* h = (const float*)d_in[0];   // [64,128,80] f32
  const float* w = (const float*)d_in[1];   // [64,1] f32
  float* Aout  = (float*)d_out;                       // [64,128,128]
  float* probs = Aout + (size_t)GB * GN * GN;         // [64]

  glcn_one<<<GB, NTHREADS, 0, stream>>>(h, w, Aout, probs);
}